// Round 11
// baseline (94.183 us; speedup 1.0000x reference)
//
#include <hip/hip_runtime.h>

// out = 0.5 * sum_over_pooled( maxpool4( x @ W^T + b ) )  -> (batch,) fp32
// x: (M=4096, K=2048) f32, W: (N=4096, K=2048) f32, b: (N,) f32, out: (M,) f32
// Strategy: cvt to bf16 in ws; 256x256 BK=32 8-wave MFMA GEMM, software-
// pipelined: ds_reads issued ONE PHASE EARLY (counted lgkm via compiler),
// 2 phases/K-tile, 1 barrier/phase, counted vmcnt(2)/(4) per phase, split
// A/B staging so no same-phase LDS read/write overlap, conflict-free
// XOR-swizzled LDS (R7-verified layout). Fused bias+maxpool4+rowsum epilogue.

typedef float  f32x4   __attribute__((ext_vector_type(4)));
typedef short  bf16x8  __attribute__((ext_vector_type(8)));
typedef short  short4v __attribute__((ext_vector_type(4)));

__device__ __forceinline__ short f2bf(float f) {
    union { float f; unsigned u; } v; v.f = f;
    unsigned r = v.u + 0x7FFFu + ((v.u >> 16) & 1u);  // round-to-nearest-even
    return (short)(r >> 16);
}

__global__ void cvt_kernel(const float* __restrict__ x, const float* __restrict__ w,
                           short* __restrict__ out, long nx, long nw) {
    long total4 = (nx + nw) >> 2;
    long stride = (long)gridDim.x * blockDim.x;
    for (long i = (long)blockIdx.x * blockDim.x + threadIdx.x; i < total4; i += stride) {
        long e = i << 2;
        const float* src = (e < nx) ? (x + e) : (w + (e - nx));
        float4 v = *(const float4*)src;
        short4v s = { f2bf(v.x), f2bf(v.y), f2bf(v.z), f2bf(v.w) };
        *(short4v*)(out + e) = s;
    }
}

// LDS layout (BK=32, R7-verified 0-conflict): chunk = 16 rows x 64B = 1KB.
// Row r, k-slice q (16B, q=0..3) at byte (r>>1)*128 + slot*16,
// slot = (q + ((r&1)<<2)) ^ ((r>>1)&7).  Staging is linear per chunk
// (global_load_lds); global source applies the inverse per lane l:
// t=(l&7)^((l>>3)&7); row = 2*(l>>3)+(t>>2); q = t&3.
// Buffers: A/B each 2 x 8192 shorts (16KB) = 32KB total LDS.

#define GLL(gp, ldsp)                                                          \
    __builtin_amdgcn_global_load_lds(                                          \
        (const __attribute__((address_space(1))) unsigned int*)(gp),           \
        (__attribute__((address_space(3))) unsigned int*)(ldsp), 16, 0, 0)

__global__ __launch_bounds__(512, 1) void gemm_pool_kernel(
    const short* __restrict__ X, const short* __restrict__ W,
    const float* __restrict__ bias, float* __restrict__ out, int K)
{
    __shared__ short As[16384];   // 2 bufs x (256 rows x 32 k) = 32 KB
    __shared__ short Bs[16384];

    const int tid  = threadIdx.x;
    const int lane = tid & 63;
    const int wid  = tid >> 6;     // 0..7
    const int wr   = wid >> 2;     // 0..1  (wave rows: 128 each)
    const int wc   = wid & 3;      // 0..3  (wave cols: 64 each)
    const int hi   = lane >> 4;    // frag k-slice q (0..3)
    const int lo   = lane & 15;    // frag row part

    // XCD-aware bijective block swizzle (nwg = 256, divisible by 8).
    const int nwg  = gridDim.x * gridDim.y;
    const int bid  = blockIdx.y * gridDim.x + blockIdx.x;
    const int wgid = (bid & 7) * (nwg >> 3) + (bid >> 3);
    const int brow = (wgid / gridDim.x) * 256;
    const int bcol = (wgid % gridDim.x) * 256;
    const int nk   = K >> 5;       // BK=32 tiles; requires nk even, >= 4

    // Fragment ds_read base (R7 formula, shorts -> bytes)
    const int rsub = ((lo >> 1) << 6) +
                     ((((hi + ((lo & 1) << 2)) ^ ((lo >> 1) & 7))) << 3);
    const char* baseA = (const char*)As + wr * 8192 + rsub * 2;  // chunk wr*8
    const char* baseB = (const char*)Bs + wc * 4096 + rsub * 2;  // chunk wc*4

    // Staging lane mapping (inverse swizzle) + running global pointers
    const int tt   = (lane & 7) ^ ((lane >> 3) & 7);
    const int grow = ((lane >> 3) << 1) + (tt >> 2);
    const int gq8  = (tt & 3) * 8;
    const short* pAa = X + (size_t)(brow + wid * 16 + grow) * K + gq8;
    const short* pAb = X + (size_t)(brow + (wid + 8) * 16 + grow) * K + gq8;
    const short* pBa = W + (size_t)(bcol + wid * 16 + grow) * K + gq8;
    const short* pBb = W + (size_t)(bcol + (wid + 8) * 16 + grow) * K + gq8;
    short* dAa = As + wid * 512;  short* dAb = As + (wid + 8) * 512;
    short* dBa = Bs + wid * 512;  short* dBb = Bs + (wid + 8) * 512;

    f32x4 acc[8][4] = {};
    bf16x8 a0[4], a1[4], bX[4], bY[4];

    // ---- prologue: stage A0,B0 (buf0) then A1,B1 (buf1); keep {A1,B1} in flight
    GLL(pAa, dAa); GLL(pAb, dAb);
    GLL(pBa, dBa); GLL(pBb, dBb);
    GLL(pAa + 32, dAa + 8192); GLL(pAb + 32, dAb + 8192);
    GLL(pBa + 32, dBa + 8192); GLL(pBb + 32, dBb + 8192);
    pAa += 64; pAb += 64; pBa += 64; pBb += 64;        // now at kt = 2
    asm volatile("s_waitcnt vmcnt(4)" ::: "memory");   // tile-0 retired
    __builtin_amdgcn_s_barrier();
    // tile-0 first-half fragments (a0 x bX), issued before the loop's p0 bar
#pragma unroll
    for (int m = 0; m < 4; ++m) a0[m] = *(const bf16x8*)(baseA + m * 1024);
#pragma unroll
    for (int n = 0; n < 4; ++n) bX[n] = *(const bf16x8*)(baseB + n * 1024);
    asm volatile("" ::: "memory");

    // p0(t): {bar; read a1(t)[buf]; stage B(t+2)->B-buf; MFMA(0,*); vmcnt(2)}
    // p1(t): {bar; read a0,b(t+1)[other buf]; stage A(t+2)->A-buf; MFMA(1,*);
    //         vmcnt(4); ptrs += 32}
    // WAR: every stage overwrites a region last read in a PRIOR phase.
    // RAW: vmcnt before each barrier gives cross-wave happens-before.
#define TILE_BODY(T, BUF, BC, BN)                                              \
    {                                                                          \
        __builtin_amdgcn_s_barrier();                                          \
        _Pragma("unroll")                                                      \
        for (int m = 0; m < 4; ++m)                                            \
            a1[m] = *(const bf16x8*)(baseA + (BUF) * 16384 + (4 + m) * 1024);  \
        if ((T) + 2 < nk) {                                                    \
            GLL(pBa, dBa + (BUF) * 8192);                                      \
            GLL(pBb, dBb + (BUF) * 8192);                                      \
        }                                                                      \
        asm volatile("" ::: "memory");                                         \
        __builtin_amdgcn_s_setprio(1);                                         \
        _Pragma("unroll")                                                      \
        for (int m = 0; m < 4; ++m)                                            \
            _Pragma("unroll")                                                  \
            for (int n = 0; n < 4; ++n)                                        \
                acc[m][n] = __builtin_amdgcn_mfma_f32_16x16x32_bf16(           \
                    a0[m], BC[n], acc[m][n], 0, 0, 0);                         \
        __builtin_amdgcn_s_setprio(0);                                         \
        if ((T) < nk - 2) asm volatile("s_waitcnt vmcnt(2)" ::: "memory");     \
        else              asm volatile("s_waitcnt vmcnt(0)" ::: "memory");     \
        __builtin_amdgcn_s_barrier();                                          \
        if ((T) + 1 < nk) {                                                    \
            _Pragma("unroll")                                                  \
            for (int m = 0; m < 4; ++m)                                        \
                a0[m] = *(const bf16x8*)(baseA + (1 - (BUF)) * 16384 + m * 1024); \
            _Pragma("unroll")                                                  \
            for (int n = 0; n < 4; ++n)                                        \
                BN[n] = *(const bf16x8*)(baseB + (1 - (BUF)) * 16384 + n * 1024); \
        }                                                                      \
        if ((T) + 2 < nk) {                                                    \
            GLL(pAa, dAa + (BUF) * 8192);                                      \
            GLL(pAb, dAb + (BUF) * 8192);                                      \
        }                                                                      \
        asm volatile("" ::: "memory");                                         \
        __builtin_amdgcn_s_setprio(1);                                         \
        _Pragma("unroll")                                                      \
        for (int m = 0; m < 4; ++m)                                            \
            _Pragma("unroll")                                                  \
            for (int n = 0; n < 4; ++n)                                        \
                acc[4 + m][n] = __builtin_amdgcn_mfma_f32_16x16x32_bf16(       \
                    a1[m], BC[n], acc[4 + m][n], 0, 0, 0);                     \
        __builtin_amdgcn_s_setprio(0);                                         \
        if ((T) < nk - 2) asm volatile("s_waitcnt vmcnt(4)" ::: "memory");     \
        else              asm volatile("s_waitcnt vmcnt(0)" ::: "memory");     \
        pAa += 32; pAb += 32; pBa += 32; pBb += 32;                            \
    }

    for (int t = 0; t < nk; t += 2) {
        TILE_BODY(t, 0, bX, bY);
        TILE_BODY(t + 1, 1, bY, bX);
    }
#undef TILE_BODY

    // Epilogue: bias + maxpool4(cols) + rowsum, fused.
    // C/D frag mapping: col = lane&15, row = (lane>>4)*4 + reg  [m89-verified]
    float bias_n[4];
#pragma unroll
    for (int nn = 0; nn < 4; ++nn)
        bias_n[nn] = bias[bcol + wc * 64 + nn * 16 + lo];

#pragma unroll
    for (int mm = 0; mm < 8; ++mm) {
#pragma unroll
        for (int j = 0; j < 4; ++j) {
            float part = 0.f;
#pragma unroll
            for (int nn = 0; nn < 4; ++nn) {
                float v = acc[mm][nn][j] + bias_n[nn];
                v = fmaxf(v, __shfl_xor(v, 1));   // pool across col bit 0
                v = fmaxf(v, __shfl_xor(v, 2));   // pool across col bit 1
                part += v;                        // lane holds pooled[(lo>>2)]
            }
            part += __shfl_xor(part, 4);          // sum the 4 pool groups
            part += __shfl_xor(part, 8);
            if (lo == 0)
                atomicAdd(&out[brow + wr * 128 + mm * 16 + hi * 4 + j], part * 0.5f);
        }
    }
}

extern "C" void kernel_launch(void* const* d_in, const int* in_sizes, int n_in,
                              void* d_out, int out_size, void* d_ws, size_t ws_size,
                              hipStream_t stream) {
    const float* x = (const float*)d_in[0];
    const float* W = (const float*)d_in[1];
    const float* b = (const float*)d_in[2];
    float* out = (float*)d_out;

    const int N = in_sizes[2];             // out_f = 4096
    const int K = in_sizes[1] / N;         // in_f  = 2048
    const int M = in_sizes[0] / K;         // batch = 4096

    // Atomics accumulate into out -> must zero every call (graph replays).
    hipMemsetAsync(out, 0, (size_t)out_size * sizeof(float), stream);

    short* xb = (short*)d_ws;
    short* wb = xb + in_sizes[0];
    cvt_kernel<<<2048, 256, 0, stream>>>(x, W, (short*)d_ws,
                                         (long)in_sizes[0], (long)in_sizes[1]);

    dim3 grid(N / 256, M / 256);           // 256 blocks
    gemm_pool_kernel<<<grid, 512, 0, stream>>>(xb, wb, b, out, K);
}